// Round 2
// baseline (106.138 us; speedup 1.0000x reference)
//
#include <hip/hip_runtime.h>
#include <hip/hip_bf16.h>

#define N_TOK 16384
#define B_DIM 8
#define C_DIM 256
#define M_ROWS (N_TOK * B_DIM)   // 131072
#define BM 64
#define NTILE (M_ROWS / BM)      // 2048
#define NBLK 256
#define TPB (NTILE / NBLK)       // 8 tiles per block

typedef __attribute__((ext_vector_type(8))) short short8;
typedef __attribute__((ext_vector_type(4))) float f32x4;

__device__ __forceinline__ unsigned short f2bf(float f) {
    union { float f; unsigned u; } v; v.f = f;
    unsigned r = v.u + 0x7fffu + ((v.u >> 16) & 1u);  // RNE
    return (unsigned short)(r >> 16);
}

__device__ __forceinline__ void gload_lds16(const void* g, void* l) {
    __builtin_amdgcn_global_load_lds(
        (const __attribute__((address_space(1))) void*)g,
        (__attribute__((address_space(3))) void*)l, 16, 0, 0);
}

// Kernel A: m = (fg_gt != 0) * (1 - mask^T) -> d_out tail; W fp32 -> bf16 ws.
__global__ __launch_bounds__(256)
void prep_kernel(const int* __restrict__ mask, const int* __restrict__ fg,
                 const float* __restrict__ W, unsigned short* __restrict__ Wbf,
                 float* __restrict__ m_out) {
    int i = blockIdx.x * 256 + threadIdx.x;
    if (i < C_DIM * C_DIM) Wbf[i] = f2bf(W[i]);
    if (i < M_ROWS) {
        int b = i & (B_DIM - 1);
        int n = i >> 3;
        m_out[i] = (fg[i] != 0) ? (1.0f - (float)mask[b * N_TOK + n]) : 0.0f;
    }
}

// Kernel B: persistent double-buffered DMA stream + MFMA + fused select.
// 512 threads (8 waves, 2x4), BM=64 rows/tile, 8 tiles/block, W in registers.
__global__ __launch_bounds__(512, 2)
void mlp_kernel(const float* __restrict__ x, const unsigned short* __restrict__ Wbf,
                const float* __restrict__ bias, const float* __restrict__ m,
                float* __restrict__ out) {
    __shared__ float lds[2][BM * C_DIM];   // 2 x 64 KB fp32, XOR-swizzled content

    const int t    = threadIdx.x;
    const int lane = t & 63;
    const int wid  = t >> 6;            // 0..7
    const int wr   = wid >> 2;          // 0..1 : row half (32 rows)
    const int wc   = wid & 3;           // 0..3 : col quarter (64 cols)
    const int lr   = lane & 15;
    const int kb   = (lane >> 4) * 8;   // k-group base within 32
    const int rsub = (lane >> 4) * 4;   // C/D row sub-block

    const int tile0 = blockIdx.x * TPB;

    // ---- Hoist bias (4 regs) and the ENTIRE W operand (128 regs) ----
    float bv[4];
    #pragma unroll
    for (int ct = 0; ct < 4; ++ct) bv[ct] = bias[wc * 64 + ct * 16 + lr];

    short8 breg[8][4];
    #pragma unroll
    for (int k8 = 0; k8 < 8; ++k8)
        #pragma unroll
        for (int ct = 0; ct < 4; ++ct)
            breg[k8][ct] = *(const short8*)(Wbf +
                (size_t)(wc * 64 + ct * 16 + lr) * C_DIM + k8 * 32 + kb);

    // ---- Stage: wave wid DMAs rows [wid*8, wid*8+8) of a tile ----
    // LDS linear dest; global source lane-addresses pre-XOR'd (rule 21).
    auto stage = [&](int buf, int tile) {
        const char* xb = (const char*)x + (size_t)tile * BM * 1024;
        #pragma unroll
        for (int r = 0; r < 8; ++r) {
            int row = wid * 8 + r;
            int src = row * 1024 + ((lane * 16) ^ ((row & 7) << 4));
            gload_lds16(xb + src, (char*)&lds[buf][0] + row * 1024);
        }
    };

    stage(0, tile0);                    // prologue: tile 0 in flight

    for (int tt = 0; tt < TPB; ++tt) {
        const int tile = tile0 + tt;
        const int cur  = tt & 1;

        // m for THIS tile, loaded BEFORE next-tile DMA (older in vmcnt order)
        float mreg[8];
        #pragma unroll
        for (int rt = 0; rt < 2; ++rt)
            #pragma unroll
            for (int r = 0; r < 4; ++r)
                mreg[rt * 4 + r] = m[tile * 64 + wr * 32 + rt * 16 + rsub + r];
        asm volatile("" ::: "memory");

        if (tt + 1 < TPB) {
            stage(cur ^ 1, tile + 1);   // 8 loads stay in flight across compute
            asm volatile("s_waitcnt vmcnt(8)" ::: "memory");
        } else {
            asm volatile("s_waitcnt vmcnt(0)" ::: "memory");
        }
        __builtin_amdgcn_s_barrier();   // buf[cur] fully staged (all waves)

        const char* Lc = (const char*)&lds[cur][0];

        f32x4 acc[2][4];
        #pragma unroll
        for (int i = 0; i < 2; ++i)
            #pragma unroll
            for (int j = 0; j < 4; ++j) acc[i][j] = (f32x4){0.f, 0.f, 0.f, 0.f};

        #pragma unroll
        for (int k8 = 0; k8 < 8; ++k8) {
            const int kk = k8 * 32;
            short8 af[2];
            #pragma unroll
            for (int rt = 0; rt < 2; ++rt) {
                int row  = wr * 32 + rt * 16 + lr;
                int base = row * 1024 + (kk + kb) * 4;
                int sz   = (row & 7) << 4;
                float4 f0 = *(const float4*)(Lc + (base ^ sz));
                float4 f1 = *(const float4*)(Lc + ((base + 16) ^ sz));
                unsigned short h[8] = { f2bf(f0.x), f2bf(f0.y), f2bf(f0.z), f2bf(f0.w),
                                        f2bf(f1.x), f2bf(f1.y), f2bf(f1.z), f2bf(f1.w) };
                af[rt] = *(const short8*)h;
            }
            #pragma unroll
            for (int rt = 0; rt < 2; ++rt)
                #pragma unroll
                for (int ct = 0; ct < 4; ++ct)
                    acc[rt][ct] = __builtin_amdgcn_mfma_f32_16x16x32_bf16(
                        af[rt], breg[k8][ct], acc[rt][ct], 0, 0, 0);
        }

        // ---- Epilogue: relu(acc+b), select vs fp32 x from LDS, store ----
        #pragma unroll
        for (int rt = 0; rt < 2; ++rt) {
            #pragma unroll
            for (int r = 0; r < 4; ++r) {
                int lrow = wr * 32 + rt * 16 + rsub + r;
                size_t grow = (size_t)tile * 64 + lrow;
                float mv = mreg[rt * 4 + r];
                #pragma unroll
                for (int ct = 0; ct < 4; ++ct) {
                    int col = wc * 64 + ct * 16 + lr;
                    float y = fmaxf(acc[rt][ct][r] + bv[ct], 0.0f);
                    int bo  = (lrow * 1024 + col * 4) ^ ((lrow & 7) << 4);
                    float xv = *(const float*)(Lc + bo);
                    out[grow * C_DIM + col] = (mv != 0.0f) ? y : xv;
                }
            }
        }

        asm volatile("" ::: "memory");
        __builtin_amdgcn_s_barrier();   // all reads of buf[cur] done before restage
    }
}

extern "C" void kernel_launch(void* const* d_in, const int* in_sizes, int n_in,
                              void* d_out, int out_size, void* d_ws, size_t ws_size,
                              hipStream_t stream) {
    const float* x    = (const float*)d_in[0];
    const int*   mask = (const int*)d_in[1];
    const int*   fg   = (const int*)d_in[2];
    const float* W    = (const float*)d_in[3];
    const float* b    = (const float*)d_in[4];

    float* out   = (float*)d_out;
    float* m_out = out + (size_t)M_ROWS * C_DIM;      // output 1: m (N,B)
    unsigned short* Wbf = (unsigned short*)d_ws;      // 128 KB scratch

    prep_kernel<<<M_ROWS / 256, 256, 0, stream>>>(mask, fg, W, Wbf, m_out);
    mlp_kernel<<<NBLK, 512, 0, stream>>>(x, Wbf, b, m_out, out);
}

// Round 3
// 72.850 us; speedup vs baseline: 1.4569x; 1.4569x over previous
//
#include <hip/hip_runtime.h>
#include <hip/hip_bf16.h>

#define N_TOK 16384
#define B_DIM 8
#define C_DIM 256
#define M_ROWS (N_TOK * B_DIM)   // 131072
#define BM 64

typedef __attribute__((ext_vector_type(8))) short short8;
typedef __attribute__((ext_vector_type(4))) float f32x4;

__device__ __forceinline__ unsigned short f2bf(float f) {
    union { float f; unsigned u; } v; v.f = f;
    unsigned r = v.u + 0x7fffu + ((v.u >> 16) & 1u);  // RNE
    return (unsigned short)(r >> 16);
}

__device__ __forceinline__ float bf2f(unsigned short h) {
    union { unsigned u; float f; } v; v.u = ((unsigned)h) << 16;
    return v.f;
}

// Kernel A: m = (fg_gt != 0) * (1 - mask^T) -> d_out tail; W fp32 -> bf16 ws.
__global__ __launch_bounds__(256)
void prep_kernel(const int* __restrict__ mask, const int* __restrict__ fg,
                 const float* __restrict__ W, unsigned short* __restrict__ Wbf,
                 float* __restrict__ m_out) {
    int i = blockIdx.x * 256 + threadIdx.x;
    if (i < C_DIM * C_DIM) Wbf[i] = f2bf(W[i]);
    if (i < M_ROWS) {
        int b = i & (B_DIM - 1);
        int n = i >> 3;
        m_out[i] = (fg[i] != 0) ? (1.0f - (float)mask[b * N_TOK + n]) : 0.0f;
    }
}

// Kernel B: one 64-row tile per block; bf16 x in LDS; W frags from L2 with
// 1-deep prefetch; epilogue entirely from LDS/registers.
__global__ __launch_bounds__(256, 4)
void mlp_kernel(const float* __restrict__ x, const unsigned short* __restrict__ Wbf,
                const float* __restrict__ bias, const float* __restrict__ m,
                float* __restrict__ out) {
    __shared__ unsigned short lds_x[BM * C_DIM];  // 32 KB bf16, XOR-swizzled
    __shared__ float lds_m[BM];

    const int t    = threadIdx.x;
    const int row0 = blockIdx.x * BM;

    // ---- Stage x tile (64 x 256 fp32 -> bf16 LDS), coalesced 32B/lane ----
    #pragma unroll
    for (int j = 0; j < 8; ++j) {
        int ci  = j * 256 + t;
        int row = ci >> 5;            // 0..63
        int cc  = (ci & 31) * 8;      // 0..248
        const float4* p = (const float4*)(x + (size_t)(row0 + row) * C_DIM + cc);
        float4 a0 = p[0];
        float4 a1 = p[1];
        unsigned short h[8] = { f2bf(a0.x), f2bf(a0.y), f2bf(a0.z), f2bf(a0.w),
                                f2bf(a1.x), f2bf(a1.y), f2bf(a1.z), f2bf(a1.w) };
        int byte = (row * 512 + cc * 2) ^ ((row & 7) << 4);
        *(int4*)((char*)lds_x + byte) = *(const int4*)h;
    }
    if (t < BM) lds_m[t] = m[row0 + t];
    __syncthreads();

    // ---- MFMA main loop: 4 waves x 64 cols, 4x4 16x16 tiles ----
    const int lane = t & 63;
    const int wid  = t >> 6;
    const int col0 = wid * 64;
    const int lr   = lane & 15;
    const int kb   = (lane >> 4) * 8;

    // Per-thread W row base pointers (4 cols tiles)
    const unsigned short* wp[4];
    #pragma unroll
    for (int ct = 0; ct < 4; ++ct)
        wp[ct] = Wbf + (size_t)(col0 + ct * 16 + lr) * C_DIM + kb;

    f32x4 acc[4][4];
    #pragma unroll
    for (int i = 0; i < 4; ++i)
        #pragma unroll
        for (int j = 0; j < 4; ++j) acc[i][j] = (f32x4){0.f, 0.f, 0.f, 0.f};

    short8 bcur[4], bnext[4];
    #pragma unroll
    for (int ct = 0; ct < 4; ++ct) bcur[ct] = *(const short8*)(wp[ct]);

    #pragma unroll
    for (int k8 = 0; k8 < 8; ++k8) {
        // prefetch next k-step's W fragments (L2-resident) one step ahead
        if (k8 < 7) {
            #pragma unroll
            for (int ct = 0; ct < 4; ++ct)
                bnext[ct] = *(const short8*)(wp[ct] + (k8 + 1) * 32);
        }
        const int kk = k8 * 32;
        short8 af[4];
        #pragma unroll
        for (int rt = 0; rt < 4; ++rt) {
            int row  = rt * 16 + lr;
            int byte = (row * 512 + (kk + kb) * 2) ^ ((row & 7) << 4);
            af[rt] = *(const short8*)((const char*)lds_x + byte);
        }
        #pragma unroll
        for (int rt = 0; rt < 4; ++rt)
            #pragma unroll
            for (int ct = 0; ct < 4; ++ct)
                acc[rt][ct] = __builtin_amdgcn_mfma_f32_16x16x32_bf16(
                    af[rt], bcur[ct], acc[rt][ct], 0, 0, 0);
        #pragma unroll
        for (int ct = 0; ct < 4; ++ct) bcur[ct] = bnext[ct];
    }

    // ---- Epilogue: relu(acc+b), select vs x (bf16 from LDS), store ----
    float bv[4];
    #pragma unroll
    for (int ct = 0; ct < 4; ++ct) bv[ct] = bias[col0 + ct * 16 + lr];

    const int rsub = (lane >> 4) * 4;   // C/D: row = (lane>>4)*4 + reg
    #pragma unroll
    for (int rt = 0; rt < 4; ++rt) {
        #pragma unroll
        for (int r = 0; r < 4; ++r) {
            int lrow = rt * 16 + rsub + r;
            float mv = lds_m[lrow];
            size_t grow = (size_t)row0 + lrow;
            #pragma unroll
            for (int ct = 0; ct < 4; ++ct) {
                int col = col0 + ct * 16 + lr;
                float y = fmaxf(acc[rt][ct][r] + bv[ct], 0.0f);
                int bo = (lrow * 512 + col * 2) ^ ((lrow & 7) << 4);
                float xv = bf2f(*(const unsigned short*)((const char*)lds_x + bo));
                out[grow * C_DIM + col] = (mv != 0.0f) ? y : xv;
            }
        }
    }
}

extern "C" void kernel_launch(void* const* d_in, const int* in_sizes, int n_in,
                              void* d_out, int out_size, void* d_ws, size_t ws_size,
                              hipStream_t stream) {
    const float* x    = (const float*)d_in[0];
    const int*   mask = (const int*)d_in[1];
    const int*   fg   = (const int*)d_in[2];
    const float* W    = (const float*)d_in[3];
    const float* b    = (const float*)d_in[4];

    float* out   = (float*)d_out;
    float* m_out = out + (size_t)M_ROWS * C_DIM;      // output 1: m (N,B)
    unsigned short* Wbf = (unsigned short*)d_ws;      // 128 KB scratch

    prep_kernel<<<M_ROWS / 256, 256, 0, stream>>>(mask, fg, W, Wbf, m_out);
    mlp_kernel<<<M_ROWS / BM, 256, 0, stream>>>(x, Wbf, b, m_out, out);
}